// Round 3
// baseline (327.694 us; speedup 1.0000x reference)
//
#include <hip/hip_runtime.h>
#include <hip/hip_bf16.h>

#define MUL_Sc 256
#define MUL_Vc 128
#define DIM_Hc 640
#define IN_COLS 644
#define KFEAT 1024
#define NT 16

#define C0F 0.05103103630798287f
#define INV_SQRT3F 0.57735026918962576f

typedef __attribute__((ext_vector_type(8))) short short8;
typedef __attribute__((ext_vector_type(4))) short bf16x4_t;
typedef __attribute__((ext_vector_type(4))) float f32x4;

#define MFMA(a, b, c) __builtin_amdgcn_mfma_f32_16x16x32_bf16((a), (b), (c), 0, 0, 0)

__device__ __forceinline__ unsigned short f2bf(float x) {
    union { float f; unsigned u; } v; v.f = x;
    unsigned r = v.u + 0x7fffu + ((v.u >> 16) & 1u);   // RNE
    return (unsigned short)(r >> 16);
}
__device__ __forceinline__ float bf2f(unsigned short h) {
    union { unsigned u; float f; } v; v.u = ((unsigned)h) << 16;
    return v.f;
}

// ---- weight prep: fp32 [k][col] -> bf16 transposed [col][k] in d_ws ----
// layout: WT_sg 384x384 (cols 0..255 = scal via W_ss/W_vv, 256..383 = gate via W_ss_g/W_vv_g)
//         WT_sv 128x256, WT_vs 128x128
__global__ void prep_weights(const float* __restrict__ Wss, const float* __restrict__ Wvv,
                             const float* __restrict__ Wssg, const float* __restrict__ Wvvg,
                             const float* __restrict__ Wsv, const float* __restrict__ Wvs,
                             unsigned short* __restrict__ wt) {
    int i = blockIdx.x * 256 + threadIdx.x;
    const int N_SG = 384 * 384;
    const int N_SV = 128 * 256;
    const int N_VS = 128 * 128;
    if (i < N_SG) {
        int col = i / 384, k = i % 384;
        float v;
        if (col < 256) v = (k < 256) ? Wss[k * 256 + col] : Wvv[(k - 256) * 256 + col];
        else { int c = col - 256; v = (k < 256) ? Wssg[k * 128 + c] : Wvvg[(k - 256) * 128 + c]; }
        wt[i] = f2bf(v);
    } else if (i < N_SG + N_SV) {
        int j = i - N_SG; int col = j >> 8, k = j & 255;
        wt[i] = f2bf(Wsv[k * 128 + col]);
    } else if (i < N_SG + N_SV + N_VS) {
        int j = i - N_SG - N_SV; int col = j >> 7, k = j & 127;
        wt[i] = f2bf(Wvs[k * 128 + col]);
    }
}

// ---- fused main kernel ----
// feature row per node (bf16, 1024): [ s0(0:256) | dot(256:384) | xs(384:640) | xv_k0(640:768) | xv_k1(768:896) | xv_k2(896:1024) ]
__global__ __launch_bounds__(512, 8)
void fused_main(const float* __restrict__ din, const unsigned short* __restrict__ wt,
                const float* __restrict__ bias, float* __restrict__ out, int N) {
    __shared__ unsigned short feat[NT * KFEAT];    // 32 KB, XOR-swizzled by (node&7)<<4
    __shared__ unsigned short sgate[NT * MUL_Vc];  // 4 KB: sigmoid(gate) as bf16
    __shared__ float psv[NT * 4];                  // ps, pv0, pv1, pv2 per node

    const int tid = threadIdx.x;
    const int n0 = blockIdx.x * NT;

    // ---------------- staging: 32 threads per node ----------------
    {
        const int g = tid >> 5;       // local node 0..15
        const int j = tid & 31;
        int n = n0 + g; if (n >= N) n = N - 1;
        const float* row = din + (size_t)n * IN_COLS;
        float ps  = row[DIM_Hc];
        float pv0 = row[DIM_Hc + 1], pv1 = row[DIM_Hc + 2], pv2 = row[DIM_Hc + 3];
        if (j == 0) { psv[g*4+0] = ps; psv[g*4+1] = pv0; psv[g*4+2] = pv1; psv[g*4+3] = pv2; }
        char* fb = (char*)feat;
        const int swz  = (g & 7) << 4;
        const int rowb = g * (KFEAT * 2);

        // xs: 8 consecutive elems per thread -> one b128 write per plane
        {
            int c = 8 * j;
            float4 x0 = *(const float4*)(row + c);
            float4 x1 = *(const float4*)(row + c + 4);
            short8 s0p, xsp;
            s0p[0]=(short)f2bf(x0.x*ps); s0p[1]=(short)f2bf(x0.y*ps); s0p[2]=(short)f2bf(x0.z*ps); s0p[3]=(short)f2bf(x0.w*ps);
            s0p[4]=(short)f2bf(x1.x*ps); s0p[5]=(short)f2bf(x1.y*ps); s0p[6]=(short)f2bf(x1.z*ps); s0p[7]=(short)f2bf(x1.w*ps);
            xsp[0]=(short)f2bf(x0.x); xsp[1]=(short)f2bf(x0.y); xsp[2]=(short)f2bf(x0.z); xsp[3]=(short)f2bf(x0.w);
            xsp[4]=(short)f2bf(x1.x); xsp[5]=(short)f2bf(x1.y); xsp[6]=(short)f2bf(x1.z); xsp[7]=(short)f2bf(x1.w);
            *(short8*)(fb + ((rowb + c * 2) ^ swz))         = s0p;
            *(short8*)(fb + ((rowb + (384 + c) * 2) ^ swz)) = xsp;
        }
        // xv: 4 consecutive u per thread -> b64 writes (dot + 3 k-planes)
        {
            int u0 = 4 * j;
            const float* p = row + MUL_Sc + 3 * u0;
            float4 q0 = *(const float4*)(p);
            float4 q1 = *(const float4*)(p + 4);
            float4 q2 = *(const float4*)(p + 8);
            // u0:   q0.x q0.y q0.z | u0+1: q0.w q1.x q1.y | u0+2: q1.z q1.w q2.x | u0+3: q2.y q2.z q2.w
            float d0 = (q0.x*pv0 + q0.y*pv1 + q0.z*pv2) * INV_SQRT3F;
            float d1 = (q0.w*pv0 + q1.x*pv1 + q1.y*pv2) * INV_SQRT3F;
            float d2 = (q1.z*pv0 + q1.w*pv1 + q2.x*pv2) * INV_SQRT3F;
            float d3 = (q2.y*pv0 + q2.z*pv1 + q2.w*pv2) * INV_SQRT3F;
            bf16x4_t dp, k0, k1, k2;
            dp[0]=(short)f2bf(d0); dp[1]=(short)f2bf(d1); dp[2]=(short)f2bf(d2); dp[3]=(short)f2bf(d3);
            k0[0]=(short)f2bf(q0.x); k0[1]=(short)f2bf(q0.w); k0[2]=(short)f2bf(q1.z); k0[3]=(short)f2bf(q2.y);
            k1[0]=(short)f2bf(q0.y); k1[1]=(short)f2bf(q1.x); k1[2]=(short)f2bf(q1.w); k1[3]=(short)f2bf(q2.z);
            k2[0]=(short)f2bf(q0.z); k2[1]=(short)f2bf(q1.y); k2[2]=(short)f2bf(q2.x); k2[3]=(short)f2bf(q2.w);
            *(bf16x4_t*)(fb + ((rowb + (256 + u0) * 2) ^ swz)) = dp;
            *(bf16x4_t*)(fb + ((rowb + (640 + u0) * 2) ^ swz)) = k0;
            *(bf16x4_t*)(fb + ((rowb + (768 + u0) * 2) ^ swz)) = k1;
            *(bf16x4_t*)(fb + ((rowb + (896 + u0) * 2) ^ swz)) = k2;
        }
    }
    __syncthreads();

    const int wave = tid >> 6;            // 0..7
    const int lane = tid & 63;
    const int l15  = lane & 15;
    const int lkb  = (lane >> 4) << 3;    // k sub-offset: 0,8,16,24
    const char* fbr = (const char*)feat;
    const int swzr = (l15 & 7) << 4;

    const unsigned short* WTsg = wt;
    const unsigned short* WTsv = wt + 384 * 384;
    const unsigned short* WTvs = wt + 384 * 384 + 128 * 256;

    // ---------------- scal+gate GEMM: K=384, 24 col-tiles, wave does {w, w+8, w+16} ----------------
    f32x4 accS[3];
    #pragma unroll
    for (int t = 0; t < 3; ++t) accS[t] = (f32x4){0,0,0,0};

    #pragma unroll
    for (int ks = 0; ks < 12; ++ks) {
        int kf = ks * 32 + lkb;
        short8 a = *(const short8*)(fbr + ((l15 * 2048 + kf * 2) ^ swzr));
        #pragma unroll
        for (int t = 0; t < 3; ++t) {
            int ct = wave + t * 8;
            short8 b = *(const short8*)(WTsg + (ct * 16 + l15) * 384 + ks * 32 + lkb);
            accS[t] = MFMA(a, b, accS[t]);
        }
    }
    {   // epilogue: scal -> silu -> global ; gate -> sigmoid -> LDS
        const int rbase = (lane >> 4) << 2;
        #pragma unroll
        for (int t = 0; t < 3; ++t) {
            int ct = wave + t * 8;
            int col = ct * 16 + l15;
            if (ct < 16) {
                float bc = bias[col];
                #pragma unroll
                for (int i = 0; i < 4; ++i) {
                    int nl = rbase + i;
                    int n = n0 + nl;
                    if (n < N) {
                        float sc = C0F * accS[t][i] + bc;
                        out[(size_t)n * DIM_Hc + col] = sc / (1.f + __expf(-sc));
                    }
                }
            } else {
                int gc = col - 256;
                #pragma unroll
                for (int i = 0; i < 4; ++i) {
                    int nl = rbase + i;
                    float gt = C0F * accS[t][i];
                    sgate[nl * MUL_Vc + gc] = f2bf(1.f / (1.f + __expf(-gt)));
                }
            }
        }
    }

    // ---------------- vec GEMMs: a1 (K=256) + v2_k (K=128 x3), wave owns u-tile = wave ----------------
    f32x4 accA, accV[3];
    accA = (f32x4){0,0,0,0};
    #pragma unroll
    for (int k = 0; k < 3; ++k) accV[k] = (f32x4){0,0,0,0};
    const int ut = wave;

    #pragma unroll
    for (int ks = 0; ks < 8; ++ks) {
        short8 b = *(const short8*)(WTsv + (ut * 16 + l15) * 256 + ks * 32 + lkb);
        int kf = 384 + ks * 32 + lkb;
        short8 a = *(const short8*)(fbr + ((l15 * 2048 + kf * 2) ^ swzr));
        accA = MFMA(a, b, accA);
    }
    #pragma unroll
    for (int ks = 0; ks < 4; ++ks) {
        short8 b = *(const short8*)(WTvs + (ut * 16 + l15) * 128 + ks * 32 + lkb);
        #pragma unroll
        for (int k = 0; k < 3; ++k) {
            int kf = 640 + 128 * k + ks * 32 + lkb;
            short8 a = *(const short8*)(fbr + ((l15 * 2048 + kf * 2) ^ swzr));
            accV[k] = MFMA(a, b, accV[k]);
        }
    }
    __syncthreads();   // sgate complete across all waves

    {   // vec epilogue: vec = C0*(a1*pv + v2*ps) * sigmoid(gate)
        const int rbase = (lane >> 4) << 2;
        int u = ut * 16 + l15;
        #pragma unroll
        for (int i = 0; i < 4; ++i) {
            int nl = rbase + i;
            int n = n0 + nl;
            if (n >= N) continue;
            float sg  = bf2f(sgate[nl * MUL_Vc + u]);
            float ps  = psv[nl * 4 + 0];
            float pv0 = psv[nl * 4 + 1], pv1 = psv[nl * 4 + 2], pv2 = psv[nl * 4 + 3];
            float av = accA[i];
            size_t ob = (size_t)n * DIM_Hc + MUL_Sc + 3 * u;
            out[ob + 0] = C0F * (av * pv0 + accV[0][i] * ps) * sg;
            out[ob + 1] = C0F * (av * pv1 + accV[1][i] * ps) * sg;
            out[ob + 2] = C0F * (av * pv2 + accV[2][i] * ps) * sg;
        }
    }
}

extern "C" void kernel_launch(void* const* d_in, const int* in_sizes, int n_in,
                              void* d_out, int out_size, void* d_ws, size_t ws_size,
                              hipStream_t stream) {
    const float* din  = (const float*)d_in[0];
    const float* Wss  = (const float*)d_in[1];
    const float* Wvv  = (const float*)d_in[2];
    const float* Wssg = (const float*)d_in[3];
    const float* Wvvg = (const float*)d_in[4];
    const float* Wsv  = (const float*)d_in[5];
    const float* Wvs  = (const float*)d_in[6];
    const float* bias = (const float*)d_in[7];
    float* out = (float*)d_out;
    unsigned short* wt = (unsigned short*)d_ws;

    const size_t WT_BYTES = (size_t)(384 * 384 + 128 * 256 + 128 * 128) * 2;
    if (ws_size < WT_BYTES) return;  // workspace too small (not expected)

    int N = in_sizes[0] / IN_COLS;

    int prep_total = 384 * 384 + 128 * 256 + 128 * 128;
    prep_weights<<<(prep_total + 255) / 256, 256, 0, stream>>>(Wss, Wvv, Wssg, Wvvg, Wsv, Wvs, wt);

    int nblocks = (N + NT - 1) / NT;
    fused_main<<<nblocks, 512, 0, stream>>>(din, wt, bias, out, N);
}

// Round 5
// 244.744 us; speedup vs baseline: 1.3389x; 1.3389x over previous
//
#include <hip/hip_runtime.h>
#include <hip/hip_bf16.h>

#define MUL_Sc 256
#define MUL_Vc 128
#define DIM_Hc 640
#define IN_COLS 644
#define KF 768
#define NT 32

#define C0F 0.05103103630798287f
#define INV_SQRT3F 0.57735026918962576f

typedef __attribute__((ext_vector_type(8))) short short8;
typedef __attribute__((ext_vector_type(4))) float f32x4;

#define MFMA(a, b, c) __builtin_amdgcn_mfma_f32_16x16x32_bf16((a), (b), (c), 0, 0, 0)

__device__ __forceinline__ unsigned short f2bf(float x) {
    union { float f; unsigned u; } v; v.f = x;
    unsigned r = v.u + 0x7fffu + ((v.u >> 16) & 1u);   // RNE
    return (unsigned short)(r >> 16);
}
__device__ __forceinline__ float bf2f(unsigned short h) {
    union { unsigned u; float f; } v; v.u = ((unsigned)h) << 16;
    return v.f;
}

// ---- weight prep: fp32 [k][col] -> bf16 transposed [col][k] in d_ws ----
// WT_sg 384x384: cols 0..255 scal (k<256: Wss, k>=256: Wvv), cols 256..383 gate (Wssg/Wvvg)
// WT_sv 128x256, WT_vs 128x128
__global__ void prep_weights(const float* __restrict__ Wss, const float* __restrict__ Wvv,
                             const float* __restrict__ Wssg, const float* __restrict__ Wvvg,
                             const float* __restrict__ Wsv, const float* __restrict__ Wvs,
                             unsigned short* __restrict__ wt) {
    int i = blockIdx.x * 256 + threadIdx.x;
    const int N_SG = 384 * 384;
    const int N_SV = 128 * 256;
    const int N_VS = 128 * 128;
    if (i < N_SG) {
        int col = i / 384, k = i % 384;
        float v;
        if (col < 256) v = (k < 256) ? Wss[k * 256 + col] : Wvv[(k - 256) * 256 + col];
        else { int c = col - 256; v = (k < 256) ? Wssg[k * 128 + c] : Wvvg[(k - 256) * 128 + c]; }
        wt[i] = f2bf(v);
    } else if (i < N_SG + N_SV) {
        int j = i - N_SG; int col = j >> 8, k = j & 255;
        wt[i] = f2bf(Wsv[k * 128 + col]);
    } else if (i < N_SG + N_SV + N_VS) {
        int j = i - N_SG - N_SV; int col = j >> 7, k = j & 127;
        wt[i] = f2bf(Wvs[k * 128 + col]);
    }
}

// ---- fused main kernel ----
// feature row per node (bf16, 768): [ xs(0:256) | dot(256:384) | xv_k0(384:512) | xv_k1(512:640) | xv_k2(640:768) ]
// after sg-GEMM the dot plane (256:384) is dead and reused as sgate[32][128] bf16.
__global__ __launch_bounds__(512, 4)
void fused_main(const float* __restrict__ din, const unsigned short* __restrict__ wt,
                const float* __restrict__ bias, float* __restrict__ out, int N) {
    __shared__ unsigned short feat[NT * KF];   // 48 KB, XOR-swizzled: byte ^= (node&7)<<4
    __shared__ float psv[NT * 4];

    const int tid = threadIdx.x;
    const int n0 = blockIdx.x * NT;

    // ---------------- staging: 16 threads per node ----------------
    {
        const int g = tid >> 4;       // local node 0..31
        const int j = tid & 15;
        int n = n0 + g; if (n >= N) n = N - 1;
        const float* row = din + (size_t)n * IN_COLS;
        float ps  = row[DIM_Hc];
        float pv0 = row[DIM_Hc + 1], pv1 = row[DIM_Hc + 2], pv2 = row[DIM_Hc + 3];
        if (j == 0) { psv[g*4+0] = ps; psv[g*4+1] = pv0; psv[g*4+2] = pv1; psv[g*4+3] = pv2; }
        char* fb = (char*)feat;
        const int swz  = (g & 7) << 4;
        const int rowb = g * (KF * 2);

        // xs: 16 consecutive elems per thread -> 2x b128 writes
        {
            int c = 16 * j;
            float4 x0 = *(const float4*)(row + c);
            float4 x1 = *(const float4*)(row + c + 4);
            float4 x2 = *(const float4*)(row + c + 8);
            float4 x3 = *(const float4*)(row + c + 12);
            short8 p0, p1;
            p0[0]=(short)f2bf(x0.x); p0[1]=(short)f2bf(x0.y); p0[2]=(short)f2bf(x0.z); p0[3]=(short)f2bf(x0.w);
            p0[4]=(short)f2bf(x1.x); p0[5]=(short)f2bf(x1.y); p0[6]=(short)f2bf(x1.z); p0[7]=(short)f2bf(x1.w);
            p1[0]=(short)f2bf(x2.x); p1[1]=(short)f2bf(x2.y); p1[2]=(short)f2bf(x2.z); p1[3]=(short)f2bf(x2.w);
            p1[4]=(short)f2bf(x3.x); p1[5]=(short)f2bf(x3.y); p1[6]=(short)f2bf(x3.z); p1[7]=(short)f2bf(x3.w);
            *(short8*)(fb + ((rowb + c * 2) ^ swz))       = p0;
            *(short8*)(fb + ((rowb + (c + 8) * 2) ^ swz)) = p1;
        }
        // xv: 8 consecutive u per thread (24 floats) -> dot + 3 k-planes, b128 each
        {
            int u0 = 8 * j;
            const float* p = row + MUL_Sc + 3 * u0;
            float e[24];
            #pragma unroll
            for (int q = 0; q < 6; ++q) {
                float4 v = *(const float4*)(p + 4 * q);
                e[4*q+0] = v.x; e[4*q+1] = v.y; e[4*q+2] = v.z; e[4*q+3] = v.w;
            }
            short8 dp, k0, k1, k2;
            #pragma unroll
            for (int m = 0; m < 8; ++m) {
                float a = e[3*m], b = e[3*m+1], c = e[3*m+2];
                dp[m] = (short)f2bf((a * pv0 + b * pv1 + c * pv2) * INV_SQRT3F);
                k0[m] = (short)f2bf(a);
                k1[m] = (short)f2bf(b);
                k2[m] = (short)f2bf(c);
            }
            *(short8*)(fb + ((rowb + (256 + u0) * 2) ^ swz)) = dp;
            *(short8*)(fb + ((rowb + (384 + u0) * 2) ^ swz)) = k0;
            *(short8*)(fb + ((rowb + (512 + u0) * 2) ^ swz)) = k1;
            *(short8*)(fb + ((rowb + (640 + u0) * 2) ^ swz)) = k2;
        }
    }
    __syncthreads();

    const int wave = tid >> 6;            // 0..7
    const int lane = tid & 63;
    const int l15  = lane & 15;
    const int lkb  = (lane >> 4) << 3;    // k sub-offset: 0,8,16,24
    const char* fbr = (const char*)feat;
    const int swzr = (l15 & 7) << 4;

    const unsigned short* WTsg = wt;
    const unsigned short* WTsv = wt + 384 * 384;
    const unsigned short* WTvs = wt + 384 * 384 + 128 * 256;

    // ---------------- sg GEMM: acc1 = xs@W (ks 0..7), acc2 = dot@W (ks 8..11) ----------------
    f32x4 acc1[3][2], acc2[3][2];
    #pragma unroll
    for (int t = 0; t < 3; ++t) {
        acc1[t][0] = (f32x4){0,0,0,0}; acc1[t][1] = (f32x4){0,0,0,0};
        acc2[t][0] = (f32x4){0,0,0,0}; acc2[t][1] = (f32x4){0,0,0,0};
    }
    const unsigned short* bp0 = WTsg + ((wave     ) * 16 + l15) * 384 + lkb;
    const unsigned short* bp1 = WTsg + ((wave +  8) * 16 + l15) * 384 + lkb;
    const unsigned short* bp2 = WTsg + ((wave + 16) * 16 + l15) * 384 + lkb;
    // depth-2 prefetch pipeline
    short8 b0a = *(const short8*)(bp0);      short8 b0b = *(const short8*)(bp0 + 32);
    short8 b1a = *(const short8*)(bp1);      short8 b1b = *(const short8*)(bp1 + 32);
    short8 b2a = *(const short8*)(bp2);      short8 b2b = *(const short8*)(bp2 + 32);
    #pragma unroll
    for (int ks = 0; ks < 12; ++ks) {
        int kf = ks * 32 + lkb;
        short8 a0 = *(const short8*)(fbr + ((l15 * 1536 + kf * 2) ^ swzr));
        short8 a1 = *(const short8*)(fbr + (((16 + l15) * 1536 + kf * 2) ^ swzr));
        short8 c0 = b0a, c1 = b1a, c2 = b2a;
        b0a = b0b; b1a = b1b; b2a = b2b;
        if (ks < 10) {
            b0b = *(const short8*)(bp0 + (ks + 2) * 32);
            b1b = *(const short8*)(bp1 + (ks + 2) * 32);
            b2b = *(const short8*)(bp2 + (ks + 2) * 32);
        }
        if (ks < 8) {
            acc1[0][0] = MFMA(a0, c0, acc1[0][0]); acc1[0][1] = MFMA(a1, c0, acc1[0][1]);
            acc1[1][0] = MFMA(a0, c1, acc1[1][0]); acc1[1][1] = MFMA(a1, c1, acc1[1][1]);
            acc1[2][0] = MFMA(a0, c2, acc1[2][0]); acc1[2][1] = MFMA(a1, c2, acc1[2][1]);
        } else {
            acc2[0][0] = MFMA(a0, c0, acc2[0][0]); acc2[0][1] = MFMA(a1, c0, acc2[0][1]);
            acc2[1][0] = MFMA(a0, c1, acc2[1][0]); acc2[1][1] = MFMA(a1, c1, acc2[1][1]);
            acc2[2][0] = MFMA(a0, c2, acc2[2][0]); acc2[2][1] = MFMA(a1, c2, acc2[2][1]);
        }
    }
    __syncthreads();   // all sg reads of dot plane done -> plane reusable for sgate

    // ---------------- vec GEMMs: a1 (xs plane, K=256) + v2_k (xv planes, K=128 x3) ----------------
    f32x4 accA[2], accV[3][2];
    accA[0] = (f32x4){0,0,0,0}; accA[1] = (f32x4){0,0,0,0};
    #pragma unroll
    for (int k = 0; k < 3; ++k) { accV[k][0] = (f32x4){0,0,0,0}; accV[k][1] = (f32x4){0,0,0,0}; }

    const unsigned short* pA = WTsv + (wave * 16 + l15) * 256 + lkb;
    const unsigned short* pV = WTvs + (wave * 16 + l15) * 128 + lkb;
    short8 va = *(const short8*)(pA);      short8 vb = *(const short8*)(pA + 32);
    #pragma unroll
    for (int ks = 0; ks < 8; ++ks) {
        int kf = ks * 32 + lkb;
        short8 a0 = *(const short8*)(fbr + ((l15 * 1536 + kf * 2) ^ swzr));
        short8 a1 = *(const short8*)(fbr + (((16 + l15) * 1536 + kf * 2) ^ swzr));
        short8 cur = va; va = vb;
        if (ks < 6) vb = *(const short8*)(pA + (ks + 2) * 32);
        accA[0] = MFMA(a0, cur, accA[0]);
        accA[1] = MFMA(a1, cur, accA[1]);
    }
    short8 wa = *(const short8*)(pV);      short8 wb = *(const short8*)(pV + 32);
    #pragma unroll
    for (int ks = 0; ks < 4; ++ks) {
        short8 cur = wa; wa = wb;
        if (ks < 2) wb = *(const short8*)(pV + (ks + 2) * 32);
        #pragma unroll
        for (int k = 0; k < 3; ++k) {
            int kf = 384 + 128 * k + ks * 32 + lkb;
            short8 a0 = *(const short8*)(fbr + ((l15 * 1536 + kf * 2) ^ swzr));
            short8 a1 = *(const short8*)(fbr + (((16 + l15) * 1536 + kf * 2) ^ swzr));
            accV[k][0] = MFMA(a0, cur, accV[k][0]);
            accV[k][1] = MFMA(a1, cur, accV[k][1]);
        }
    }

    // ---------------- sg epilogue: scal -> silu -> global ; gate -> sigmoid -> dot plane ----------------
    {
        const int rbase = (lane >> 4) << 2;
        float pss[2][4];
        #pragma unroll
        for (int s = 0; s < 2; ++s)
        #pragma unroll
        for (int i = 0; i < 4; ++i) pss[s][i] = psv[(s * 16 + rbase + i) * 4];

        #pragma unroll
        for (int t = 0; t < 2; ++t) {
            int col = (wave + t * 8) * 16 + l15;
            float bc = bias[col];
            #pragma unroll
            for (int s = 0; s < 2; ++s)
            #pragma unroll
            for (int i = 0; i < 4; ++i) {
                int nl = s * 16 + rbase + i;
                int n = n0 + nl;
                if (n < N) {
                    float sc = C0F * (pss[s][i] * acc1[t][s][i] + acc2[t][s][i]) + bc;
                    out[(size_t)n * DIM_Hc + col] = sc / (1.f + __expf(-sc));
                }
            }
        }
        // gate tile: cols wave*16+l15 of the 128 gate outputs
        char* fbw = (char*)feat;
        int gc = wave * 16 + l15;
        #pragma unroll
        for (int s = 0; s < 2; ++s)
        #pragma unroll
        for (int i = 0; i < 4; ++i) {
            int nl = s * 16 + rbase + i;
            float gt = C0F * (pss[s][i] * acc1[2][s][i] + acc2[2][s][i]);
            unsigned short sg = f2bf(1.f / (1.f + __expf(-gt)));
            *(unsigned short*)(fbw + ((nl * 1536 + (256 + gc) * 2) ^ ((nl & 7) << 4))) = sg;
        }
    }
    __syncthreads();   // sgate visible to all waves

    // ---------------- vec epilogue ----------------
    {
        const int rbase = (lane >> 4) << 2;
        int u = wave * 16 + l15;
        #pragma unroll
        for (int s = 0; s < 2; ++s)
        #pragma unroll
        for (int i = 0; i < 4; ++i) {
            int nl = s * 16 + rbase + i;
            int n = n0 + nl;
            if (n >= N) continue;
            float sg  = bf2f(*(const unsigned short*)(fbr + ((nl * 1536 + (256 + u) * 2) ^ ((nl & 7) << 4))));
            float ps  = psv[nl * 4 + 0];
            float pv0 = psv[nl * 4 + 1], pv1 = psv[nl * 4 + 2], pv2 = psv[nl * 4 + 3];
            float av = accA[s][i];
            size_t ob = (size_t)n * DIM_Hc + MUL_Sc + 3 * u;
            out[ob + 0] = C0F * (av * pv0 + accV[0][s][i] * ps) * sg;
            out[ob + 1] = C0F * (av * pv1 + accV[1][s][i] * ps) * sg;
            out[ob + 2] = C0F * (av * pv2 + accV[2][s][i] * ps) * sg;
        }
    }
}

extern "C" void kernel_launch(void* const* d_in, const int* in_sizes, int n_in,
                              void* d_out, int out_size, void* d_ws, size_t ws_size,
                              hipStream_t stream) {
    const float* din  = (const float*)d_in[0];
    const float* Wss  = (const float*)d_in[1];
    const float* Wvv  = (const float*)d_in[2];
    const float* Wssg = (const float*)d_in[3];
    const float* Wvvg = (const float*)d_in[4];
    const float* Wsv  = (const float*)d_in[5];
    const float* Wvs  = (const float*)d_in[6];
    const float* bias = (const float*)d_in[7];
    float* out = (float*)d_out;
    unsigned short* wt = (unsigned short*)d_ws;

    const size_t WT_BYTES = (size_t)(384 * 384 + 128 * 256 + 128 * 128) * 2;
    if (ws_size < WT_BYTES) return;

    int N = in_sizes[0] / IN_COLS;

    int prep_total = 384 * 384 + 128 * 256 + 128 * 128;
    prep_weights<<<(prep_total + 255) / 256, 256, 0, stream>>>(Wss, Wvv, Wssg, Wvvg, Wsv, Wvs, wt);

    int nblocks = (N + NT - 1) / NT;
    fused_main<<<nblocks, 512, 0, stream>>>(din, wt, bias, out, N);
}